// Round 9
// baseline (88.885 us; speedup 1.0000x reference)
//
#include <hip/hip_runtime.h>

// Problem constants
#define BB 8
#define CIN 16
#define COUT 64
#define HH 32
#define WW 32

// denom = 2*N_EKV*VT = 0.075. Pre-scaled log2-units:
//   x' = x*C, th' = clip(theta,1,8)*C, C = log2(e)/0.075; b1 = x'-th'
//   e2 = e1 * 2^(-0.1*C).  Reference clip(a,-50,20) == post-log
//   l = min(log2(1+2^b), B_HI) (fp32-exact; see earlier rounds).
//   d >= 1.6: both l's hit B_HI -> cancel exactly. d <= -0.72: f < 5e-9 -> skip.
#define SCALE_C 19.235933878519388f /* (1/0.075)*log2(e) */
#define K2E 0.26359713811472845f    /* 2^(-0.1*SCALE_C) = e^(-4/3) */
#define B_HI 28.85390081777927f     /* 20*log2e */
#define WINLO_S (-13.849872392533959f) /* -0.72 * SCALE_C */
#define OUT_CONST (0.4804530139182014f * 0.05625f * 0.1f) /* ln2^2*ALPHA*R */

#define EXP2F(x) __builtin_amdgcn_exp2f(x)
#define LOG2F(x) __builtin_amdgcn_logf(x)

// LDS x-slice per phase: 8 cins x 10 rows (tile rows -1..8) x 34 cols (-1..32)
#define XROWS 10
#define XCOLS 34
#define XPLANE (XROWS * XCOLS) // 340
#define PHASE_CINS 8
#define STAGE_ELEMS (PHASE_CINS * XPLANE) // 2720

struct Tap {
    float th;  // clip(theta)*SCALE_C
    int off4;  // byte offset within s_x for this tap: (cinL*340 + dy*34 + dx)*4
};

// Sort each co's 144 taps by theta, partitioned into two 72-tap phases
// (cin 0-7, cin 8-15), ascending theta within phase. Rank-sort via LDS.
__global__ __launch_bounds__(192) void sort_kernel(const float* __restrict__ theta,
                                                   Tap* __restrict__ taps) {
    int co = blockIdx.x;
    int j = threadIdx.x;
    __shared__ float s_thv[144];
    float thv = 0.0f;
    int off4 = 0;
    if (j < 144) {
        int cin = j / 9, k = j - cin * 9;
        int dy = k / 3, dx = k - dy * 3;
        thv = fminf(fmaxf(theta[co * 144 + j], 1.0f), 8.0f) * SCALE_C;
        off4 = ((cin & 7) * XPLANE + dy * XCOLS + dx) * 4;
        s_thv[j] = thv;
    }
    __syncthreads();
    if (j < 144) {
        int base = (j / 72) * 72; // phase segment
        int rank = 0;
        for (int i = 0; i < 72; ++i) {
            float o = s_thv[base + i];
            rank += (o < thv) || (o == thv && (base + i) < j);
        }
        Tap e;
        e.th = thv;
        e.off4 = off4;
        taps[co * 144 + base + rank] = e;
    }
}

__device__ __forceinline__ void eval_tap(float v, float th, float& acc) {
    float b1 = v - th;
    float e1 = EXP2F(b1);
    float e2 = e1 * K2E;
    float l1 = fminf(LOG2F(1.0f + e1), B_HI);
    float l2 = fminf(LOG2F(1.0f + e2), B_HI);
    acc = fmaf(l1, l1, acc);
    acc = fmaf(-l2, l2, acc);
}

// Block mapping = R7's XCD-aware decode: b = bid&7 (XCD id), tile=(bid>>3)&3,
// co = (bid>>8)*8 + ((bid>>5)&7) -> co-resident blocks share the (b,tile) slice.
// Per phase: stage x*C into LDS, block-max -> scalar cutoff, then iterate ONLY
// the sorted active prefix (theta' < smax - WINLO_S): no per-tap branch for
// inactive taps, straight-line eval for active ones.
__global__ __launch_bounds__(256, 8) void ekv_kernel(const float* __restrict__ x,
                                                     const Tap* __restrict__ taps,
                                                     const float* __restrict__ scale,
                                                     float* __restrict__ out) {
    int bid = blockIdx.x;
    int b = bid & 7;
    int tile = (bid >> 3) & 3;
    int co = (bid >> 8) * 8 + ((bid >> 5) & 7);

    int t = threadIdx.x;
    int ow = t & 31;
    int ohl = t >> 5;
    int oh = tile * 8 + ohl;

    __shared__ __align__(16) float s_x[STAGE_ELEMS]; // 10.6KB
    __shared__ float s_red[4];

    const float* xb = x + (size_t)b * (CIN * HH * WW);
    const Tap* tp = taps + co * 144;
    const char* s_xb = (const char*)s_x;
    int pix4 = (ohl * XCOLS + ow) * 4;

    float acc0 = 0.0f, acc1 = 0.0f;

#pragma unroll 1
    for (int phase = 0; phase < 2; ++phase) {
        if (phase) __syncthreads(); // protect s_x/s_red reuse

        // Stage 8 cins x 10 x 34, bounds-checked, pre-scaled; track running max.
        float m = -1e30f;
#pragma unroll 1
        for (int i = t; i < STAGE_ELEMS; i += 256) {
            int cinL = i / XPLANE;
            int rem = i - cinL * XPLANE;
            int r = rem / XCOLS;
            int c = rem - r * XCOLS;
            int gy = tile * 8 + r - 1;
            int gx = c - 1;
            float v = 0.0f;
            if ((unsigned)gy < HH && (unsigned)gx < WW)
                v = xb[((phase * PHASE_CINS + cinL) * HH + gy) * WW + gx] * SCALE_C;
            s_x[i] = v;
            m = fmaxf(m, v);
        }
        // Block max: wave butterfly then 4-slot LDS combine.
#pragma unroll
        for (int d2 = 32; d2; d2 >>= 1) m = fmaxf(m, __shfl_xor(m, d2));
        if ((t & 63) == 0) s_red[t >> 6] = m;
        __syncthreads();
        m = fmaxf(fmaxf(s_red[0], s_red[1]), fmaxf(s_red[2], s_red[3]));
        float cut = __builtin_amdgcn_readfirstlane(m) - WINLO_S;

        // Active-prefix loop over this phase's sorted 72 taps.
        const Tap* tpp = tp + phase * 72;
#pragma unroll 1
        for (int i = 0; i < 72; i += 2) {
            Tap e0 = tpp[i];
            if (e0.th >= cut) break;
            float v0 = *(const float*)(s_xb + (pix4 + e0.off4));
            eval_tap(v0, e0.th, acc0);
            Tap e1 = tpp[i + 1];
            if (e1.th >= cut) break;
            float v1 = *(const float*)(s_xb + (pix4 + e1.off4));
            eval_tap(v1, e1.th, acc1);
        }
    }

    float sc = scale[0] * (OUT_CONST);
    out[(((size_t)b * COUT + co) * HH + oh) * WW + ow] = (acc0 + acc1) * sc;
}

extern "C" void kernel_launch(void* const* d_in, const int* in_sizes, int n_in,
                              void* d_out, int out_size, void* d_ws, size_t ws_size,
                              hipStream_t stream) {
    const float* x = (const float*)d_in[0];
    const float* theta = (const float*)d_in[1];
    const float* scale = (const float*)d_in[2];
    float* out = (float*)d_out;

    Tap* taps = (Tap*)d_ws; // 64*144*8B = 73.7KB, rebuilt every call
    (void)ws_size; (void)in_sizes; (void)n_in; (void)out_size;

    sort_kernel<<<COUT, 192, 0, stream>>>(theta, taps);
    ekv_kernel<<<BB * 4 * COUT, 256, 0, stream>>>(x, taps, scale, out);
}

// Round 10
// 86.636 us; speedup vs baseline: 1.0260x; 1.0260x over previous
//
#include <hip/hip_runtime.h>

// Problem constants
#define BB 8
#define CIN 16
#define COUT 64
#define HH 32
#define WW 32
#define PH 34
#define PW 34
#define PPLANE (PH * PW) // 1156

// denom = 2*N_EKV*VT = 0.075. Pre-scaled log2-units:
//   xp = x*C, th' = clip(theta,1,8)*C, C = log2(e)/0.075; b1 = xp - th'
//   e2 = e1 * 2^(-0.1*C).  Reference clip(a,-50,20) == post-log
//   l = min(log2(1+2^b), B_HI) (fp32-exact): b >= B_HI -> log2(1+2^b)==b;
//   b <= -30 -> 1+2^b rounds to 1 -> l = 0. d >= 1.6: both l's hit B_HI ->
//   cancel exactly. Small b1: exp2 underflows to 0 -> l = 0 -> f = 0.
// => the eval below is valid for ALL b1 with no clamps and no branches.
#define SCALE_C 19.235933878519388f /* (1/0.075)*log2(e) */
#define K2E 0.26359713811472845f    /* 2^(-0.1*SCALE_C) = e^(-4/3) */
#define B_HI 28.85390081777927f     /* 20*log2e */
#define OUT_CONST (0.4804530139182014f * 0.05625f * 0.1f) /* ln2^2*ALPHA*R */

#define EXP2F(x) __builtin_amdgcn_exp2f(x)
#define LOG2F(x) __builtin_amdgcn_logf(x)

#define NTH (COUT * CIN * 9) // 9216

// blocks 0..577: pad+prescale x into xp ([8][16][34][34]);
// blocks 578..613: prescale clipped theta (9216 elems).
__global__ __launch_bounds__(256) void init_kernel(const float* __restrict__ x,
                                                   const float* __restrict__ theta,
                                                   float* __restrict__ xp,
                                                   float* __restrict__ thp) {
    if (blockIdx.x < 578) {
        int idx = blockIdx.x * 256 + threadIdx.x; // 578*256 = 147968 exactly
        int c = idx / PPLANE;
        int r = idx - c * PPLANE;
        int y = r / PW;
        int xc = r - y * PW;
        float v = 0.0f;
        if (y >= 1 && y <= HH && xc >= 1 && xc <= WW) {
            v = x[c * (HH * WW) + (y - 1) * WW + (xc - 1)] * SCALE_C;
        }
        xp[idx] = v;
    } else {
        int i = (blockIdx.x - 578) * 256 + threadIdx.x;
        if (i < NTH) {
            thp[i] = fminf(fmaxf(theta[i], 1.0f), 8.0f) * SCALE_C;
        }
    }
}

__device__ __forceinline__ void load9(const float* __restrict__ p, float* v) {
#pragma unroll
    for (int dy = 0; dy < 3; ++dy)
#pragma unroll
        for (int dx = 0; dx < 3; ++dx)
            v[dy * 3 + dx] = p[dy * PW + dx];
}

// BRANCHLESS: all 9 taps evaluated straight-line. 9 independent chains ->
// the scheduler interleaves trans/VALU across taps; no v_cmp->s_cbranch
// fences, no vcc hazards. thp[k] block-uniform -> SGPR operands.
__device__ __forceinline__ void compute9(const float* v, const float* __restrict__ thp,
                                         float* acc) {
#pragma unroll
    for (int k = 0; k < 9; ++k) {
        float b1 = v[k] - thp[k];
        float e1 = EXP2F(b1);
        float e2 = e1 * K2E;
        float l1 = fminf(LOG2F(1.0f + e1), B_HI);
        float l2 = fminf(LOG2F(1.0f + e2), B_HI);
        float a = acc[k % 3];
        a = fmaf(l1, l1, a);
        a = fmaf(-l2, l2, a);
        acc[k % 3] = a;
    }
}

// Block mapping = R7's XCD-aware decode: b = bid&7 (XCD id), tile=(bid>>3)&3,
// co = (bid>>8)*8 + ((bid>>5)&7) -> 8 co-resident blocks/CU share the same
// (b,tile) 26KB x-slice (L1-hot). 2048 blocks = 8 blocks/CU = 8 waves/SIMD
// (max occupancy; launch_bounds(256,8) caps VGPR at 64).
__global__ __launch_bounds__(256, 8) void ekv_kernel(const float* __restrict__ xp,
                                                     const float* __restrict__ thp,
                                                     const float* __restrict__ scale,
                                                     float* __restrict__ out) {
    int bid = blockIdx.x;
    int b = bid & 7;
    int tile = (bid >> 3) & 3;
    int co = (bid >> 8) * 8 + ((bid >> 5) & 7);

    int t = threadIdx.x;
    int ow = t & 31;
    int oh = tile * 8 + (t >> 5);

    const float* thc = thp + co * (CIN * 9);
    const float* p0 = xp + (size_t)b * (CIN * PPLANE) + oh * PW + ow;

    float acc[3] = {0.0f, 0.0f, 0.0f};

    // Register ping-pong over cin: prefetch next plane's 9 taps while current
    // plane's 9 evals run.
    float va[9], vb[9];
    load9(p0, va);
#pragma unroll 1
    for (int cin = 0; cin < CIN; cin += 2) {
        load9(p0 + (cin + 1) * PPLANE, vb);
        compute9(va, thc + cin * 9, acc);
        int nc = cin + 2 < CIN ? cin + 2 : CIN - 1; // clamp: harmless re-read
        load9(p0 + nc * PPLANE, va);
        compute9(vb, thc + (cin + 1) * 9, acc);
    }

    float sc = scale[0] * (OUT_CONST);
    out[(((size_t)b * COUT + co) * HH + oh) * WW + ow] =
        (acc[0] + acc[1] + acc[2]) * sc;
}

extern "C" void kernel_launch(void* const* d_in, const int* in_sizes, int n_in,
                              void* d_out, int out_size, void* d_ws, size_t ws_size,
                              hipStream_t stream) {
    const float* x = (const float*)d_in[0];
    const float* theta = (const float*)d_in[1];
    const float* scale = (const float*)d_in[2];
    float* out = (float*)d_out;

    // ws layout: [0, 36KB) prescaled theta (9216 f32); then padded x (147968 f32)
    float* thp = (float*)d_ws;
    float* xp = thp + NTH;
    (void)ws_size;

    init_kernel<<<578 + (NTH + 255) / 256, 256, 0, stream>>>(x, theta, xp, thp);
    ekv_kernel<<<BB * 4 * COUT, 256, 0, stream>>>(xp, thp, scale, out);
}

// Round 11
// 74.772 us; speedup vs baseline: 1.1888x; 1.1587x over previous
//
#include <hip/hip_runtime.h>

// Problem constants
#define BB 8
#define CIN 16
#define COUT 64
#define HH 32
#define WW 32
// padded plane: 34 rows x 36 cols (cols -1..34; rows -1..32). Row = 144B.
#define PH 34
#define PW 36
#define PPLANE (PH * PW) // 1224

// denom = 2*N_EKV*VT = 0.075. Pre-scaled log2-units:
//   xp = x*C, th' = clip(theta,1,8)*C, C = log2(e)/0.075; b1 = xp - th'
//   e2 = e1 * 2^(-0.1*C).  Reference clip(a,-50,20) == post-log
//   l = min(log2(1+2^b), B_HI) (fp32-exact; see earlier rounds).
//   d >= 1.6: both l's hit B_HI -> cancel exactly. d <= -0.72: f < 5e-9 -> skip.
#define SCALE_C 19.235933878519388f /* (1/0.075)*log2(e) */
#define K2E 0.26359713811472845f    /* 2^(-0.1*SCALE_C) = e^(-4/3) */
#define B_HI 28.85390081777927f     /* 20*log2e */
#define WINLO_S (-13.849872392533959f) /* -0.72 * SCALE_C */
#define OUT_CONST (0.4804530139182014f * 0.05625f * 0.1f) /* ln2^2*ALPHA*R */

#define EXP2F(x) __builtin_amdgcn_exp2f(x)
#define LOG2F(x) __builtin_amdgcn_logf(x)

#define NTH (COUT * CIN * 9) // 9216
#define PAD_ELEMS (BB * CIN * PPLANE) // 156672 = 612*256

// blocks 0..611: pad+prescale x into xp ([8][16][34][36]);
// blocks 612..647: prescale clipped theta (9216 elems).
__global__ __launch_bounds__(256) void init_kernel(const float* __restrict__ x,
                                                   const float* __restrict__ theta,
                                                   float* __restrict__ xp,
                                                   float* __restrict__ thp) {
    if (blockIdx.x < 612) {
        int idx = blockIdx.x * 256 + threadIdx.x; // 612*256 = 156672 exactly
        int c = idx / PPLANE;
        int r = idx - c * PPLANE;
        int y = r / PW;
        int xc = r - y * PW;
        float v = 0.0f;
        if (y >= 1 && y <= HH && xc >= 1 && xc <= WW) {
            v = x[c * (HH * WW) + (y - 1) * WW + (xc - 1)] * SCALE_C;
        }
        xp[idx] = v;
    } else {
        int i = (blockIdx.x - 612) * 256 + threadIdx.x;
        if (i < NTH) {
            thp[i] = fminf(fmaxf(theta[i], 1.0f), 8.0f) * SCALE_C;
        }
    }
}

// One align-4 dwordx4 per tap-row: cols ow..ow+3 (padded), taps use x/y/z.
// 3 VMEM instrs per cin instead of 9 -> 48 per thread instead of 144.
__device__ __forceinline__ void load12(const float* __restrict__ p, float4* v) {
#pragma unroll
    for (int dy = 0; dy < 3; ++dy)
        __builtin_memcpy(&v[dy], p + dy * PW, 16);
}

// Branchy eval (best-known from R7): wave-any skip, SGPR theta operands.
__device__ __forceinline__ void compute9(const float4* v, const float* __restrict__ thp,
                                         float* acc) {
#pragma unroll
    for (int dy = 0; dy < 3; ++dy) {
        float row[3] = {v[dy].x, v[dy].y, v[dy].z};
#pragma unroll
        for (int dx = 0; dx < 3; ++dx) {
            float b1 = row[dx] - thp[dy * 3 + dx];
            if (__any(b1 > WINLO_S)) {
                float e1 = EXP2F(b1);
                float e2 = e1 * K2E;
                float l1 = fminf(LOG2F(1.0f + e1), B_HI);
                float l2 = fminf(LOG2F(1.0f + e2), B_HI);
                float a = acc[dx];
                a = fmaf(l1, l1, a);
                a = fmaf(-l2, l2, a);
                acc[dx] = a;
            }
        }
    }
}

// Block mapping = R7's XCD-aware decode: b = bid&7 (XCD id), tile=(bid>>3)&3,
// co = (bid>>8)*8 + ((bid>>5)&7) -> 8 co-resident blocks/CU share the same
// (b,tile) x-slice. 2048 blocks -> 8 blocks/CU -> 8 waves/SIMD.
__global__ __launch_bounds__(256, 8) void ekv_kernel(const float* __restrict__ xp,
                                                     const float* __restrict__ thp,
                                                     const float* __restrict__ scale,
                                                     float* __restrict__ out) {
    int bid = blockIdx.x;
    int b = bid & 7;
    int tile = (bid >> 3) & 3;
    int co = (bid >> 8) * 8 + ((bid >> 5) & 7);

    int t = threadIdx.x;
    int ow = t & 31;
    int oh = tile * 8 + (t >> 5);

    const float* thc = thp + co * (CIN * 9);
    // Pixel (oh,ow): taps at padded rows oh..oh+2, padded cols ow..ow+2.
    const float* p0 = xp + (size_t)b * (CIN * PPLANE) + oh * PW + ow;

    float acc[3] = {0.0f, 0.0f, 0.0f};

    // Register ping-pong over cin: prefetch next plane's 3 dwordx4 rows while
    // current plane's 9 evals run.
    float4 va[3], vb[3];
    load12(p0, va);
#pragma unroll 1
    for (int cin = 0; cin < CIN; cin += 2) {
        load12(p0 + (cin + 1) * PPLANE, vb);
        compute9(va, thc + cin * 9, acc);
        int nc = cin + 2 < CIN ? cin + 2 : CIN - 1; // clamp: harmless re-read
        load12(p0 + nc * PPLANE, va);
        compute9(vb, thc + (cin + 1) * 9, acc);
    }

    float sc = scale[0] * (OUT_CONST);
    out[(((size_t)b * COUT + co) * HH + oh) * WW + ow] =
        (acc[0] + acc[1] + acc[2]) * sc;
}

extern "C" void kernel_launch(void* const* d_in, const int* in_sizes, int n_in,
                              void* d_out, int out_size, void* d_ws, size_t ws_size,
                              hipStream_t stream) {
    const float* x = (const float*)d_in[0];
    const float* theta = (const float*)d_in[1];
    const float* scale = (const float*)d_in[2];
    float* out = (float*)d_out;

    // ws layout: [0, 36KB) prescaled theta (9216 f32); then padded x (156672 f32)
    float* thp = (float*)d_ws;
    float* xp = thp + NTH;
    (void)ws_size;

    init_kernel<<<612 + (NTH + 255) / 256, 256, 0, stream>>>(x, theta, xp, thp);
    ekv_kernel<<<BB * 4 * COUT, 256, 0, stream>>>(xp, thp, scale, out);
}